// Round 7
// baseline (239.038 us; speedup 1.0000x reference)
//
#include <hip/hip_runtime.h>
#include <cmath>

#define EPS 1e-5f
#define SZ 2097152  // N*H*W*E = 4*64*64*128

typedef __attribute__((ext_vector_type(8))) short short8;   // 8 bf16 (4 VGPRs)
typedef __attribute__((ext_vector_type(4))) float floatx4;  // MFMA C/D frag

__device__ __forceinline__ float dot4(float4 a, float4 b) {
  return fmaf(a.x, b.x, fmaf(a.y, b.y, fmaf(a.z, b.z, a.w * b.w)));
}

__device__ __forceinline__ short f2bf(float f) {
  union { float f; unsigned u; } v; v.f = f;
  unsigned r = v.u + 0x7fff + ((v.u >> 16) & 1);  // RNE
  return (short)(r >> 16);
}

// row-band XCD swizzle: each XCD owns 64 consecutive logical blocks.
__device__ __forceinline__ int xcd_band(int bid) {
  return (bid & 7) * 64 + (bid >> 3);
}

#define MFMA16(a, b, c) __builtin_amdgcn_mfma_f32_16x16x32_bf16(a, b, c, 0, 0, 0)

// ---------------------------------------------------------------- K1: LN1 + QKV (LDS-staged fp32->bf16 weights) + prep epilogue
// round-6 verbatim. grid 512, block 512
__global__ __launch_bounds__(512) void k_qkvln(const float* __restrict__ x,
    const float* __restrict__ g, const float* __restrict__ b,
    const float* __restrict__ wq, const float* __restrict__ wk,
    const float* __restrict__ wv, const float* __restrict__ bq,
    const float* __restrict__ bk, const float* __restrict__ bv,
    const float* __restrict__ w1, const float* __restrict__ w2,
    const float* __restrict__ bil_w, const float* __restrict__ qcoeff,
    float* __restrict__ xnhwc, short* __restrict__ qbf,
    short* __restrict__ kbf, short* __restrict__ vtb,
    short* __restrict__ w1bf, short* __restrict__ w2bf, short* __restrict__ tb) {
  __shared__ float tile[128 * 33];
  __shared__ float mres[32], rres[32];
  __shared__ __align__(16) short xs[32 * 136];
  __shared__ __align__(16) short ws[128 * 136];
  int tid = threadIdx.x;
  int l = xcd_band(blockIdx.x);
  int half = l & 1, ny = l >> 1;
  int n = ny >> 6, y = ny & 63;
  const float* xb = x + (size_t)n * 524288 + y * 64 + half * 32;
  for (int it = 0; it < 8; ++it) {
    int flat = it * 512 + tid;
    int c = flat >> 5, xpl = flat & 31;
    tile[c * 33 + xpl] = xb[(size_t)c * 4096 + xpl];
  }
  __syncthreads();
  {
    int pxl = tid >> 4, cl = tid & 15;
    float s = 0.f, sq = 0.f;
#pragma unroll
    for (int j = 0; j < 8; ++j) {
      float v = tile[(cl * 8 + j) * 33 + pxl];
      s += v; sq += v * v;
    }
    s += __shfl_xor(s, 1);  sq += __shfl_xor(sq, 1);
    s += __shfl_xor(s, 2);  sq += __shfl_xor(sq, 2);
    s += __shfl_xor(s, 4);  sq += __shfl_xor(sq, 4);
    s += __shfl_xor(s, 8);  sq += __shfl_xor(sq, 8);
    if (cl == 0) {
      float m = s * (1.f / 128.f);
      float var = sq * (1.f / 128.f) - m * m;
      mres[pxl] = m;
      rres[pxl] = rsqrtf(var + EPS);
    }
  }
  __syncthreads();
  size_t rowbase = (size_t)ny * 8192 + half * 4096;
  for (int it = 0; it < 8; ++it) {
    int flat = it * 512 + tid;
    int c = flat & 127, pxl = flat >> 7;
    float v = tile[c * 33 + pxl];
    xnhwc[rowbase + flat] = v;
    xs[pxl * 136 + c] = f2bf((v - mres[pxl]) * rres[pxl] * g[c] + b[c]);
  }
  __syncthreads();
  int w = tid >> 6, lane = tid & 63;
  int quad = lane >> 4, r16 = lane & 15;
  int wm = w & 1, wn = w >> 1;
  int stripl = wm * 16;
  short8 a[4];
#pragma unroll
  for (int kk = 0; kk < 4; ++kk)
    a[kk] = *(const short8*)&xs[(stripl + r16) * 136 + kk * 32 + quad * 8];
  const float* wptr[3] = {wq, wk, wv};
  const float* bptr[3] = {bq, bk, bv};
  for (int m = 0; m < 3; ++m) {
    __syncthreads();
    const float* wp = wptr[m];
    for (int i = tid; i < 2048; i += 512) {
      int e = i * 8;
      float4 v0 = *(const float4*)&wp[e];
      float4 v1 = *(const float4*)&wp[e + 4];
      short t8[8] = {f2bf(v0.x), f2bf(v0.y), f2bf(v0.z), f2bf(v0.w),
                     f2bf(v1.x), f2bf(v1.y), f2bf(v1.z), f2bf(v1.w)};
      int o = e >> 7, c = e & 127;
      *(uint4*)&ws[o * 136 + c] = *(uint4*)t8;
    }
    __syncthreads();
    const float* bb = bptr[m];
#pragma unroll
    for (int nt = 0; nt < 2; ++nt) {
      int o0 = wn * 32 + nt * 16;
      floatx4 acc = {0.f, 0.f, 0.f, 0.f};
#pragma unroll
      for (int kk = 0; kk < 4; ++kk) {
        short8 bfr = *(const short8*)&ws[(o0 + r16) * 136 + kk * 32 + quad * 8];
        acc = MFMA16(a[kk], bfr, acc);
      }
      float bv2 = bb[o0 + r16];
      if (m < 2) {
        short* dst = (m == 0) ? qbf : kbf;
#pragma unroll
        for (int r = 0; r < 4; ++r) {
          int pxl = stripl + quad * 4 + r;
          dst[rowbase + pxl * 128 + o0 + r16] = f2bf(acc[r] + bv2);
        }
      } else {
        short t4[4] = {f2bf(acc[0] + bv2), f2bf(acc[1] + bv2),
                       f2bf(acc[2] + bv2), f2bf(acc[3] + bv2)};
        *(uint2*)&vtb[(size_t)(n * 128 + o0 + r16) * 4096 + y * 64 + half * 32 +
                      stripl + quad * 4] = *(uint2*)t4;
      }
    }
  }
  // prep epilogue (distributed; no barriers)
  int gtid = blockIdx.x * 512 + tid;
  if (gtid < 8192) {
    int e = gtid * 8, f = e >> 7, c = e & 127;
    float4 v0 = *(const float4*)&w1[e], v1 = *(const float4*)&w1[e + 4];
    short t8[8] = {f2bf(v0.x), f2bf(v0.y), f2bf(v0.z), f2bf(v0.w),
                   f2bf(v1.x), f2bf(v1.y), f2bf(v1.z), f2bf(v1.w)};
    *(uint4*)&w1bf[f * 136 + c] = *(uint4*)t8;
  } else if (gtid < 16384) {
    int e = (gtid - 8192) * 8, o = e >> 9, j = e & 511, ck = j >> 7, jj = j & 127;
    float4 v0 = *(const float4*)&w2[e], v1 = *(const float4*)&w2[e + 4];
    short t8[8] = {f2bf(v0.x), f2bf(v0.y), f2bf(v0.z), f2bf(v0.w),
                   f2bf(v1.x), f2bf(v1.y), f2bf(v1.z), f2bf(v1.w)};
    *(uint4*)&w2bf[(ck * 128 + o) * 136 + jj] = *(uint4*)t8;
  } else if (gtid < 81920) {
    int idx = gtid - 16384;
    int nn = idx >> 14, oi = idx & 16383;
    const float* wrow = bil_w + (size_t)oi * 64;
    const float* qc = qcoeff + nn * 64;
    float acc = 0.f;
#pragma unroll
    for (int q = 0; q < 64; q += 4) {
      float4 w4 = *(const float4*)&wrow[q];
      float4 q4 = *(const float4*)&qc[q];
      acc = fmaf(w4.x, q4.x, fmaf(w4.y, q4.y, fmaf(w4.z, q4.z, fmaf(w4.w, q4.w, acc))));
    }
    int o = oi >> 7, i = oi & 127;
    tb[nn * 17408 + o * 136 + i] = f2bf(acc);
  }
}

// ---------------------------------------------------------------- K2a: attention -> z3g bf16 (round-5 verbatim)
__global__ __launch_bounds__(512, 3) void k_attn(const short* __restrict__ qbf,
    const short* __restrict__ kbf, const short* __restrict__ vtb,
    const float* __restrict__ rel_bias, short* __restrict__ z3g) {
  __shared__ __align__(16) char smem[44672];
  int tid = threadIdx.x;
  int l = xcd_band(blockIdx.x);
  int half = l & 1, ny = l >> 1;
  int n = ny >> 6, y = ny & 63;
  int w16 = tid >> 6, lane = tid & 63;
  int quad = lane >> 4, r16 = lane & 15;
  size_t rowbase = (size_t)ny * 8192;
  int h = w16 >> 1, swl = w16 & 1;
  int sg = half * 2 + swl;
  int strip = sg * 16;
  float* ssfw = (float*)(smem + w16 * 3200);
  short* Abw = (short*)(smem + 25600 + w16 * 2176);
  float* biasw = (float*)(smem + 43008 + w16 * 208);
  const short* qrow = qbf + (size_t)n * 524288 + (size_t)y * 8192 + h * 32;
  const short* kbp = kbf + (size_t)n * 524288 + h * 32;
  short8 qf = *(const short8*)&qrow[(strip + r16) * 128 + quad * 8];
  short8 kf[7][2];
#pragma unroll
  for (int r = 0; r < 7; ++r) {
    int yyc = min(max(y + r - 3, 0), 63);
#pragma unroll
    for (int t = 0; t < 2; ++t) {
      int gxc = min(max((sg + t) * 16 + r16 - 3, 0), 63);
      kf[r][t] = *(const short8*)&kbp[(size_t)(yyc * 64 + gxc) * 128 + quad * 8];
    }
  }
  {
    unsigned* ad = (unsigned*)Abw;
    for (int i = lane; i < 544; i += 64) ad[i] = 0u;
  }
  if (lane < 49) biasw[lane] = rel_bias[h * 49 + lane];
#pragma unroll
  for (int r = 0; r < 7; ++r) {
    bool yok = (unsigned)(y + r - 3) < 64u;
#pragma unroll
    for (int t = 0; t < 2; ++t) {
      int xxc = (sg + t) * 16 + r16;
      bool ok = yok && ((unsigned)(xxc - 3) < 64u);
      floatx4 c = MFMA16(qf, kf[r][t], ((floatx4){0.f, 0.f, 0.f, 0.f}));
#pragma unroll
      for (int rr = 0; rr < 4; ++rr) {
        int lrow = quad * 4 + rr;
        int dx = xxc - (strip + lrow);
        if ((unsigned)dx < 7u) {
          float val = ok ? c[rr] : 0.f;
          ssfw[lrow * 50 + r * 7 + dx] = val + biasw[r * 7 + dx];
        }
      }
    }
  }
  {
    int lrow = lane >> 2, sub = lane & 3;
    int p0 = sub * 12;
    float sv[13];
    float mx = -1e30f;
#pragma unroll
    for (int pi = 0; pi < 13; ++pi) {
      sv[pi] = ssfw[lrow * 50 + p0 + pi];
      mx = fmaxf(mx, sv[pi]);
    }
    mx = fmaxf(mx, __shfl_xor(mx, 1));
    mx = fmaxf(mx, __shfl_xor(mx, 2));
    float sum = 0.f;
#pragma unroll
    for (int pi = 0; pi < 13; ++pi) {
      float e = __expf(sv[pi] - mx);
      if (pi == 12 && sub != 3) e = 0.f;
      sv[pi] = e; sum += e;
    }
    sum += __shfl_xor(sum, 1);
    sum += __shfl_xor(sum, 2);
    float inv = 1.f / sum;
#pragma unroll
    for (int pi = 0; pi < 13; ++pi)
      if (pi < 12 || sub == 3) ssfw[lrow * 50 + p0 + pi] = sv[pi] * inv;
  }
  floatx4 oacc[2] = {(floatx4){0.f, 0.f, 0.f, 0.f}, (floatx4){0.f, 0.f, 0.f, 0.f}};
  int lrow = lane >> 2, sub = lane & 3;
  int pxg = strip + lrow;
  const short* vbp = vtb + (size_t)(n * 128 + h * 32) * 4096;
  short8 vf[2][2][2];
  {
    int yyc0 = min(max(y - 3, 0), 63);
#pragma unroll
    for (int kk = 0; kk < 2; ++kk)
#pragma unroll
      for (int nt = 0; nt < 2; ++nt)
        vf[0][kk][nt] = *(const short8*)&vbp[(size_t)(nt * 16 + r16) * 4096 + yyc0 * 64 + kk * 32 + quad * 8];
  }
#pragma unroll
  for (int r = 0; r < 7; ++r) {
    if (r < 6) {
      int yycn = min(max(y + r - 2, 0), 63);
#pragma unroll
      for (int kk = 0; kk < 2; ++kk)
#pragma unroll
        for (int nt = 0; nt < 2; ++nt)
          vf[(r + 1) & 1][kk][nt] = *(const short8*)&vbp[(size_t)(nt * 16 + r16) * 4096 + yycn * 64 + kk * 32 + quad * 8];
    }
    int c0 = pxg + sub - 3;
    if ((unsigned)c0 < 64u) Abw[lrow * 68 + c0] = f2bf(ssfw[lrow * 50 + r * 7 + sub]);
    int c1 = pxg + sub + 1;
    if (sub < 3 && (unsigned)c1 < 64u)
      Abw[lrow * 68 + c1] = f2bf(ssfw[lrow * 50 + r * 7 + sub + 4]);
    if ((unsigned)(y + r - 3) < 64u) {
#pragma unroll
      for (int kk = 0; kk < 2; ++kk) {
        short8 af = *(const short8*)&Abw[r16 * 68 + kk * 32 + quad * 8];
#pragma unroll
        for (int nt = 0; nt < 2; ++nt)
          oacc[nt] = MFMA16(af, vf[r & 1][kk][nt], oacc[nt]);
      }
    }
  }
#pragma unroll
  for (int nt = 0; nt < 2; ++nt)
#pragma unroll
    for (int rr = 0; rr < 4; ++rr) {
      int px = half * 32 + swl * 16 + quad * 4 + rr;
      z3g[rowbase + px * 128 + h * 32 + nt * 16 + r16] = f2bf(oacc[nt][rr]);
    }
}

// ---------------------------------------------------------------- KD: attention diagnostic, x4 internal reps (y rotated), scratch out
// DIAGNOSTIC ONLY: dur/4 = attention-phase time; counters = pure attention profile.
__global__ __launch_bounds__(512, 3) void kd_attn(const short* __restrict__ qbf,
    const short* __restrict__ kbf, const short* __restrict__ vtb,
    const float* __restrict__ rel_bias, short* __restrict__ z3d) {
  __shared__ __align__(16) char smem[44672];
  int tid = threadIdx.x;
  int l = xcd_band(blockIdx.x);
  int half = l & 1, ny0 = l >> 1;
  int n = ny0 >> 6;
  int w16 = tid >> 6, lane = tid & 63;
  int quad = lane >> 4, r16 = lane & 15;
  int h = w16 >> 1, swl = w16 & 1;
  int sg = half * 2 + swl;
  int strip = sg * 16;
  float* ssfw = (float*)(smem + w16 * 3200);
  short* Abw = (short*)(smem + 25600 + w16 * 2176);
  float* biasw = (float*)(smem + 43008 + w16 * 208);
  for (int rep = 0; rep < 4; ++rep) {
    int y = ((ny0 & 63) + rep * 17) & 63;        // rotate row per rep: defeats CSE, stays L2-hot
    size_t rowbase = (size_t)((ny0 & ~63) + y) * 8192;
    const short* qrow = qbf + (size_t)n * 524288 + (size_t)y * 8192 + h * 32;
    const short* kbp = kbf + (size_t)n * 524288 + h * 32;
    short8 qf = *(const short8*)&qrow[(strip + r16) * 128 + quad * 8];
    short8 kf[7][2];
#pragma unroll
    for (int r = 0; r < 7; ++r) {
      int yyc = min(max(y + r - 3, 0), 63);
#pragma unroll
      for (int t = 0; t < 2; ++t) {
        int gxc = min(max((sg + t) * 16 + r16 - 3, 0), 63);
        kf[r][t] = *(const short8*)&kbp[(size_t)(yyc * 64 + gxc) * 128 + quad * 8];
      }
    }
    {
      unsigned* ad = (unsigned*)Abw;
      for (int i = lane; i < 544; i += 64) ad[i] = 0u;
    }
    if (lane < 49) biasw[lane] = rel_bias[h * 49 + lane];
#pragma unroll
    for (int r = 0; r < 7; ++r) {
      bool yok = (unsigned)(y + r - 3) < 64u;
#pragma unroll
      for (int t = 0; t < 2; ++t) {
        int xxc = (sg + t) * 16 + r16;
        bool ok = yok && ((unsigned)(xxc - 3) < 64u);
        floatx4 c = MFMA16(qf, kf[r][t], ((floatx4){0.f, 0.f, 0.f, 0.f}));
#pragma unroll
        for (int rr = 0; rr < 4; ++rr) {
          int lrow = quad * 4 + rr;
          int dx = xxc - (strip + lrow);
          if ((unsigned)dx < 7u) {
            float val = ok ? c[rr] : 0.f;
            ssfw[lrow * 50 + r * 7 + dx] = val + biasw[r * 7 + dx];
          }
        }
      }
    }
    {
      int lrow = lane >> 2, sub = lane & 3;
      int p0 = sub * 12;
      float sv[13];
      float mx = -1e30f;
#pragma unroll
      for (int pi = 0; pi < 13; ++pi) {
        sv[pi] = ssfw[lrow * 50 + p0 + pi];
        mx = fmaxf(mx, sv[pi]);
      }
      mx = fmaxf(mx, __shfl_xor(mx, 1));
      mx = fmaxf(mx, __shfl_xor(mx, 2));
      float sum = 0.f;
#pragma unroll
      for (int pi = 0; pi < 13; ++pi) {
        float e = __expf(sv[pi] - mx);
        if (pi == 12 && sub != 3) e = 0.f;
        sv[pi] = e; sum += e;
      }
      sum += __shfl_xor(sum, 1);
      sum += __shfl_xor(sum, 2);
      float inv = 1.f / sum;
#pragma unroll
      for (int pi = 0; pi < 13; ++pi)
        if (pi < 12 || sub == 3) ssfw[lrow * 50 + p0 + pi] = sv[pi] * inv;
    }
    floatx4 oacc[2] = {(floatx4){0.f, 0.f, 0.f, 0.f}, (floatx4){0.f, 0.f, 0.f, 0.f}};
    int lrow = lane >> 2, sub = lane & 3;
    int pxg = strip + lrow;
    const short* vbp = vtb + (size_t)(n * 128 + h * 32) * 4096;
    short8 vf[2][2][2];
    {
      int yyc0 = min(max(y - 3, 0), 63);
#pragma unroll
      for (int kk = 0; kk < 2; ++kk)
#pragma unroll
        for (int nt = 0; nt < 2; ++nt)
          vf[0][kk][nt] = *(const short8*)&vbp[(size_t)(nt * 16 + r16) * 4096 + yyc0 * 64 + kk * 32 + quad * 8];
    }
#pragma unroll
    for (int r = 0; r < 7; ++r) {
      if (r < 6) {
        int yycn = min(max(y + r - 2, 0), 63);
#pragma unroll
        for (int kk = 0; kk < 2; ++kk)
#pragma unroll
          for (int nt = 0; nt < 2; ++nt)
            vf[(r + 1) & 1][kk][nt] = *(const short8*)&vbp[(size_t)(nt * 16 + r16) * 4096 + yycn * 64 + kk * 32 + quad * 8];
      }
      int c0 = pxg + sub - 3;
      if ((unsigned)c0 < 64u) Abw[lrow * 68 + c0] = f2bf(ssfw[lrow * 50 + r * 7 + sub]);
      int c1 = pxg + sub + 1;
      if (sub < 3 && (unsigned)c1 < 64u)
        Abw[lrow * 68 + c1] = f2bf(ssfw[lrow * 50 + r * 7 + sub + 4]);
      if ((unsigned)(y + r - 3) < 64u) {
#pragma unroll
        for (int kk = 0; kk < 2; ++kk) {
          short8 af = *(const short8*)&Abw[r16 * 68 + kk * 32 + quad * 8];
#pragma unroll
          for (int nt = 0; nt < 2; ++nt)
            oacc[nt] = MFMA16(af, vf[r & 1][kk][nt], oacc[nt]);
        }
      }
    }
#pragma unroll
    for (int nt = 0; nt < 2; ++nt)
#pragma unroll
      for (int rr = 0; rr < 4; ++rr) {
        int px = half * 32 + swl * 16 + quad * 4 + rr;
        z3d[rowbase + px * 128 + h * 32 + nt * 16 + r16] = f2bf(oacc[nt][rr]);
      }
  }
}

// ---------------------------------------------------------------- K2b: bilinear + LN2 + FFN + out
// round-5 tail + h1s double-buffer (1 barrier/FFN-chunk instead of 2); LDS 43008 -> 3 blocks/CU
__global__ __launch_bounds__(512, 4) void k_tail(const short* __restrict__ z3g,
    const short* __restrict__ tb, const float* __restrict__ bil_b,
    const float* __restrict__ xnhwc, const float* __restrict__ g2,
    const float* __restrict__ b2ln, const short* __restrict__ w1bf,
    const float* __restrict__ b1, const short* __restrict__ w2bf,
    const float* __restrict__ b2, float* __restrict__ out) {
  __shared__ __align__(16) char smem[43008];
  short* z3s = (short*)smem;                    // [32][136] bf16 (LN2 out)
  float* z2s = (float*)(smem + 8704);           // [32][132] f32
  short* h1a = (short*)(smem + 25600);          // [32][136] bf16 (even chunks)
  short* h1b = (short*)(smem + 34304);          // [32][136] bf16 (odd chunks)
  int tid = threadIdx.x;
  int l = xcd_band(blockIdx.x);
  int half = l & 1, ny = l >> 1;
  int n = ny >> 6, y = ny & 63;
  int w16 = tid >> 6, lane = tid & 63;
  int quad = lane >> 4, r16 = lane & 15;
  size_t rowbase = (size_t)ny * 8192;
  int wm = w16 & 1, wn = w16 >> 1;
  int stripL = wm * 16;
  const short* tn = tb + (size_t)n * 17408;
  short8 tf[2][4];
#pragma unroll
  for (int nt = 0; nt < 2; ++nt)
#pragma unroll
    for (int kk = 0; kk < 4; ++kk)
      tf[nt][kk] = *(const short8*)&tn[(wn * 32 + nt * 16 + r16) * 136 + kk * 32 + quad * 8];
  float xres[2][4];
#pragma unroll
  for (int nt = 0; nt < 2; ++nt)
#pragma unroll
    for (int r = 0; r < 4; ++r)
      xres[nt][r] = xnhwc[rowbase + (half * 32 + stripL + quad * 4 + r) * 128 +
                          wn * 32 + nt * 16 + r16];
  // bilinear: A from z3g (same-XCD L2), B = tf
  {
    short8 a[4];
#pragma unroll
    for (int kk = 0; kk < 4; ++kk)
      a[kk] = *(const short8*)&z3g[rowbase + (half * 32 + stripL + r16) * 128 + kk * 32 + quad * 8];
#pragma unroll
    for (int nt = 0; nt < 2; ++nt) {
      int o0 = wn * 32 + nt * 16;
      floatx4 acc = {0.f, 0.f, 0.f, 0.f};
#pragma unroll
      for (int kk = 0; kk < 4; ++kk)
        acc = MFMA16(a[kk], tf[nt][kk], acc);
      float bb = bil_b[o0 + r16];
#pragma unroll
      for (int r = 0; r < 4; ++r) {
        int pxl = stripL + quad * 4 + r;
        z2s[pxl * 132 + o0 + r16] = acc[r] + bb + xres[nt][r];
      }
    }
  }
  __syncthreads();
  // LN2 -> z3s bf16 (w1 chunk0 prefetch issued first)
  short8 wA[2][4];
#pragma unroll
  for (int nt = 0; nt < 2; ++nt)
#pragma unroll
    for (int kk = 0; kk < 4; ++kk)
      wA[nt][kk] = *(const short8*)&w1bf[(wn * 32 + nt * 16 + r16) * 136 + kk * 32 + quad * 8];
  {
    int px = tid >> 4, cl = tid & 15;
    float4 v0 = *(const float4*)&z2s[px * 132 + cl * 8];
    float4 v1 = *(const float4*)&z2s[px * 132 + cl * 8 + 4];
    float s = v0.x + v0.y + v0.z + v0.w + v1.x + v1.y + v1.z + v1.w;
    float sq = dot4(v0, v0) + dot4(v1, v1);
    s += __shfl_xor(s, 1);  sq += __shfl_xor(sq, 1);
    s += __shfl_xor(s, 2);  sq += __shfl_xor(sq, 2);
    s += __shfl_xor(s, 4);  sq += __shfl_xor(sq, 4);
    s += __shfl_xor(s, 8);  sq += __shfl_xor(sq, 8);
    float m = s * (1.f / 128.f);
    float var = sq * (1.f / 128.f) - m * m;
    float rr = rsqrtf(var + EPS);
    int c0 = cl * 8;
    short t8[8];
#pragma unroll
    for (int j = 0; j < 8; ++j) {
      float vv = (j < 4) ? (&v0.x)[j] : (&v1.x)[j - 4];
      t8[j] = f2bf((vv - m) * rr * g2[c0 + j] + b2ln[c0 + j]);
    }
    *(uint4*)&z3s[px * 136 + c0] = *(uint4*)t8;
  }
  __syncthreads();
  // FFN: 4 chunks, h1s double-buffered -> ONE barrier per chunk
  floatx4 zacc[2];
  zacc[0] = (floatx4){0.f, 0.f, 0.f, 0.f};
  zacc[1] = (floatx4){0.f, 0.f, 0.f, 0.f};
#pragma unroll
  for (int fc = 0; fc < 512; fc += 128) {
    short* h1w = ((fc >> 7) & 1) ? h1b : h1a;
    short8 wB[2][4];
#pragma unroll
    for (int nt = 0; nt < 2; ++nt)
#pragma unroll
      for (int kk = 0; kk < 4; ++kk)
        wB[nt][kk] = *(const short8*)&w2bf[((fc >> 7) * 128 + wn * 32 + nt * 16 + r16) * 136 + kk * 32 + quad * 8];
    float bb1v[2];
    bb1v[0] = b1[fc + wn * 32 + r16];
    bb1v[1] = b1[fc + wn * 32 + 16 + r16];
    short8 a3[4];
#pragma unroll
    for (int kk = 0; kk < 4; ++kk)
      a3[kk] = *(const short8*)&z3s[(stripL + r16) * 136 + kk * 32 + quad * 8];
    floatx4 hacc[2];
#pragma unroll
    for (int nt = 0; nt < 2; ++nt) {
      hacc[nt] = (floatx4){0.f, 0.f, 0.f, 0.f};
#pragma unroll
      for (int kk = 0; kk < 4; ++kk)
        hacc[nt] = MFMA16(a3[kk], wA[nt][kk], hacc[nt]);
    }
    if (fc < 384) {
#pragma unroll
      for (int nt = 0; nt < 2; ++nt)
#pragma unroll
        for (int kk = 0; kk < 4; ++kk)
          wA[nt][kk] = *(const short8*)&w1bf[(fc + 128 + wn * 32 + nt * 16 + r16) * 136 + kk * 32 + quad * 8];
    }
#pragma unroll
    for (int nt = 0; nt < 2; ++nt) {
      int f0 = wn * 32 + nt * 16;
#pragma unroll
      for (int r = 0; r < 4; ++r) {
        float hv = hacc[nt][r] + bb1v[nt];
        float ge = 0.5f * hv * (1.f + erff(hv * 0.70710678118f));
        h1w[(stripL + quad * 4 + r) * 136 + f0 + r16] = f2bf(ge);
      }
    }
    __syncthreads();   // writes of this chunk visible; prev-prev buffer reads done 2 barriers ago
    short8 ah[4];
#pragma unroll
    for (int kk = 0; kk < 4; ++kk)
      ah[kk] = *(const short8*)&h1w[(stripL + r16) * 136 + kk * 32 + quad * 8];
#pragma unroll
    for (int nt = 0; nt < 2; ++nt)
#pragma unroll
      for (int kk = 0; kk < 4; ++kk)
        zacc[nt] = MFMA16(ah[kk], wB[nt][kk], zacc[nt]);
    // no trailing barrier: next chunk writes the OTHER h1 buffer
  }
  // epilogue: direct float4 stores
#pragma unroll
  for (int nt = 0; nt < 2; ++nt) {
    int o = wn * 32 + nt * 16 + r16;
    float bb = b2[o];
    float res[4];
#pragma unroll
    for (int r = 0; r < 4; ++r)
      res[r] = zacc[nt][r] + bb + z2s[(stripL + quad * 4 + r) * 132 + o];
    *(float4*)&out[(((size_t)(n * 128 + o)) * 64 + y) * 64 + half * 32 + stripL + quad * 4] =
        *(float4*)res;
  }
}

// ----------------------------------------------------------------
extern "C" void kernel_launch(void* const* d_in, const int* in_sizes, int n_in,
                              void* d_out, int out_size, void* d_ws, size_t ws_size,
                              hipStream_t stream) {
  const float* x        = (const float*)d_in[0];
  const float* qcoeff   = (const float*)d_in[1];
  const float* wq       = (const float*)d_in[2];
  const float* bq       = (const float*)d_in[3];
  const float* wk       = (const float*)d_in[4];
  const float* bk       = (const float*)d_in[5];
  const float* wv       = (const float*)d_in[6];
  const float* bv       = (const float*)d_in[7];
  const float* rel_bias = (const float*)d_in[8];
  const float* ln1_g    = (const float*)d_in[9];
  const float* ln1_b    = (const float*)d_in[10];
  const float* bil_w    = (const float*)d_in[11];
  const float* bil_b    = (const float*)d_in[12];
  const float* ln2_g    = (const float*)d_in[13];
  const float* ln2_b    = (const float*)d_in[14];
  const float* w1       = (const float*)d_in[15];
  const float* b1       = (const float*)d_in[16];
  const float* w2       = (const float*)d_in[17];
  const float* b2       = (const float*)d_in[18];
  float* out = (float*)d_out;

  float* ws = (float*)d_ws;
  float* x_nhwc = ws;                    // [N,H,W,E] fp32
  short* qbf = (short*)(ws + 2 * SZ);
  short* kbf = qbf + SZ;
  short* vtb = kbf + SZ;
  short* bf     = (short*)(ws + 4 * SZ);
  short* tb     = bf;                    // [4][128][136]
  short* w1bf   = bf + 4 * 17408;        // [512][136]
  short* w2bf   = w1bf + 512 * 136;      // [4][128][136]
  short* z3g    = w2bf + 4 * 17408;      // [N,H,W,E] bf16 attn out
  short* z3d    = z3g + SZ;              // diagnostic scratch

  k_qkvln<<<512, 512, 0, stream>>>(x, ln1_g, ln1_b, wq, wk, wv, bq, bk, bv,
                                   w1, w2, bil_w, qcoeff,
                                   x_nhwc, qbf, kbf, vtb, w1bf, w2bf, tb);
  k_attn<<<512, 512, 0, stream>>>(qbf, kbf, vtb, rel_bias, z3g);
  k_tail<<<512, 512, 0, stream>>>(z3g, tb, bil_b, x_nhwc, ln2_g, ln2_b,
                                  w1bf, b1, w2bf, b2, out);
  // diagnostic last: cannot perturb production; writes scratch only
  kd_attn<<<512, 512, 0, stream>>>(qbf, kbf, vtb, rel_bias, z3d);
}

// Round 8
// 149.231 us; speedup vs baseline: 1.6018x; 1.6018x over previous
//
#include <hip/hip_runtime.h>
#include <cmath>

#define EPS 1e-5f
#define SZ 2097152  // N*H*W*E = 4*64*64*128

typedef __attribute__((ext_vector_type(8))) short short8;   // 8 bf16 (4 VGPRs)
typedef __attribute__((ext_vector_type(4))) float floatx4;  // MFMA C/D frag

__device__ __forceinline__ float dot4(float4 a, float4 b) {
  return fmaf(a.x, b.x, fmaf(a.y, b.y, fmaf(a.z, b.z, a.w * b.w)));
}

__device__ __forceinline__ short f2bf(float f) {
  union { float f; unsigned u; } v; v.f = f;
  unsigned r = v.u + 0x7fff + ((v.u >> 16) & 1);  // RNE
  return (short)(r >> 16);
}

// row-band XCD swizzle: each XCD owns 64 consecutive logical blocks.
__device__ __forceinline__ int xcd_band(int bid) {
  return (bid & 7) * 64 + (bid >> 3);
}

#define MFMA16(a, b, c) __builtin_amdgcn_mfma_f32_16x16x32_bf16(a, b, c, 0, 0, 0)

// ---------------------------------------------------------------- K1: LN1 + QKV (LDS-staged fp32->bf16 weights) + prep epilogue
// round-6 verbatim. grid 512, block 512
__global__ __launch_bounds__(512) void k_qkvln(const float* __restrict__ x,
    const float* __restrict__ g, const float* __restrict__ b,
    const float* __restrict__ wq, const float* __restrict__ wk,
    const float* __restrict__ wv, const float* __restrict__ bq,
    const float* __restrict__ bk, const float* __restrict__ bv,
    const float* __restrict__ w1, const float* __restrict__ w2,
    const float* __restrict__ bil_w, const float* __restrict__ qcoeff,
    float* __restrict__ xnhwc, short* __restrict__ qbf,
    short* __restrict__ kbf, short* __restrict__ vtb,
    short* __restrict__ w1bf, short* __restrict__ w2bf, short* __restrict__ tb) {
  __shared__ float tile[128 * 33];
  __shared__ float mres[32], rres[32];
  __shared__ __align__(16) short xs[32 * 136];
  __shared__ __align__(16) short ws[128 * 136];
  int tid = threadIdx.x;
  int l = xcd_band(blockIdx.x);
  int half = l & 1, ny = l >> 1;
  int n = ny >> 6, y = ny & 63;
  const float* xb = x + (size_t)n * 524288 + y * 64 + half * 32;
  for (int it = 0; it < 8; ++it) {
    int flat = it * 512 + tid;
    int c = flat >> 5, xpl = flat & 31;
    tile[c * 33 + xpl] = xb[(size_t)c * 4096 + xpl];
  }
  __syncthreads();
  {
    int pxl = tid >> 4, cl = tid & 15;
    float s = 0.f, sq = 0.f;
#pragma unroll
    for (int j = 0; j < 8; ++j) {
      float v = tile[(cl * 8 + j) * 33 + pxl];
      s += v; sq += v * v;
    }
    s += __shfl_xor(s, 1);  sq += __shfl_xor(sq, 1);
    s += __shfl_xor(s, 2);  sq += __shfl_xor(sq, 2);
    s += __shfl_xor(s, 4);  sq += __shfl_xor(sq, 4);
    s += __shfl_xor(s, 8);  sq += __shfl_xor(sq, 8);
    if (cl == 0) {
      float m = s * (1.f / 128.f);
      float var = sq * (1.f / 128.f) - m * m;
      mres[pxl] = m;
      rres[pxl] = rsqrtf(var + EPS);
    }
  }
  __syncthreads();
  size_t rowbase = (size_t)ny * 8192 + half * 4096;
  for (int it = 0; it < 8; ++it) {
    int flat = it * 512 + tid;
    int c = flat & 127, pxl = flat >> 7;
    float v = tile[c * 33 + pxl];
    xnhwc[rowbase + flat] = v;
    xs[pxl * 136 + c] = f2bf((v - mres[pxl]) * rres[pxl] * g[c] + b[c]);
  }
  __syncthreads();
  int w = tid >> 6, lane = tid & 63;
  int quad = lane >> 4, r16 = lane & 15;
  int wm = w & 1, wn = w >> 1;
  int stripl = wm * 16;
  short8 a[4];
#pragma unroll
  for (int kk = 0; kk < 4; ++kk)
    a[kk] = *(const short8*)&xs[(stripl + r16) * 136 + kk * 32 + quad * 8];
  const float* wptr[3] = {wq, wk, wv};
  const float* bptr[3] = {bq, bk, bv};
  for (int m = 0; m < 3; ++m) {
    __syncthreads();
    const float* wp = wptr[m];
    for (int i = tid; i < 2048; i += 512) {
      int e = i * 8;
      float4 v0 = *(const float4*)&wp[e];
      float4 v1 = *(const float4*)&wp[e + 4];
      short t8[8] = {f2bf(v0.x), f2bf(v0.y), f2bf(v0.z), f2bf(v0.w),
                     f2bf(v1.x), f2bf(v1.y), f2bf(v1.z), f2bf(v1.w)};
      int o = e >> 7, c = e & 127;
      *(uint4*)&ws[o * 136 + c] = *(uint4*)t8;
    }
    __syncthreads();
    const float* bb = bptr[m];
#pragma unroll
    for (int nt = 0; nt < 2; ++nt) {
      int o0 = wn * 32 + nt * 16;
      floatx4 acc = {0.f, 0.f, 0.f, 0.f};
#pragma unroll
      for (int kk = 0; kk < 4; ++kk) {
        short8 bfr = *(const short8*)&ws[(o0 + r16) * 136 + kk * 32 + quad * 8];
        acc = MFMA16(a[kk], bfr, acc);
      }
      float bv2 = bb[o0 + r16];
      if (m < 2) {
        short* dst = (m == 0) ? qbf : kbf;
#pragma unroll
        for (int r = 0; r < 4; ++r) {
          int pxl = stripl + quad * 4 + r;
          dst[rowbase + pxl * 128 + o0 + r16] = f2bf(acc[r] + bv2);
        }
      } else {
        short t4[4] = {f2bf(acc[0] + bv2), f2bf(acc[1] + bv2),
                       f2bf(acc[2] + bv2), f2bf(acc[3] + bv2)};
        *(uint2*)&vtb[(size_t)(n * 128 + o0 + r16) * 4096 + y * 64 + half * 32 +
                      stripl + quad * 4] = *(uint2*)t4;
      }
    }
  }
  // prep epilogue (distributed; no barriers)
  int gtid = blockIdx.x * 512 + tid;
  if (gtid < 8192) {
    int e = gtid * 8, f = e >> 7, c = e & 127;
    float4 v0 = *(const float4*)&w1[e], v1 = *(const float4*)&w1[e + 4];
    short t8[8] = {f2bf(v0.x), f2bf(v0.y), f2bf(v0.z), f2bf(v0.w),
                   f2bf(v1.x), f2bf(v1.y), f2bf(v1.z), f2bf(v1.w)};
    *(uint4*)&w1bf[f * 136 + c] = *(uint4*)t8;
  } else if (gtid < 16384) {
    int e = (gtid - 8192) * 8, o = e >> 9, j = e & 511, ck = j >> 7, jj = j & 127;
    float4 v0 = *(const float4*)&w2[e], v1 = *(const float4*)&w2[e + 4];
    short t8[8] = {f2bf(v0.x), f2bf(v0.y), f2bf(v0.z), f2bf(v0.w),
                   f2bf(v1.x), f2bf(v1.y), f2bf(v1.z), f2bf(v1.w)};
    *(uint4*)&w2bf[(ck * 128 + o) * 136 + jj] = *(uint4*)t8;
  } else if (gtid < 81920) {
    int idx = gtid - 16384;
    int nn = idx >> 14, oi = idx & 16383;
    const float* wrow = bil_w + (size_t)oi * 64;
    const float* qc = qcoeff + nn * 64;
    float acc = 0.f;
#pragma unroll
    for (int q = 0; q < 64; q += 4) {
      float4 w4 = *(const float4*)&wrow[q];
      float4 q4 = *(const float4*)&qc[q];
      acc = fmaf(w4.x, q4.x, fmaf(w4.y, q4.y, fmaf(w4.z, q4.z, fmaf(w4.w, q4.w, acc))));
    }
    int o = oi >> 7, i = oi & 127;
    tb[nn * 17408 + o * 136 + i] = f2bf(acc);
  }
}

// ---------------------------------------------------------------- K2: attention + bilinear + LN2 + FFN + out (merged)
// v8: PV single K=32 chunk (x0=strip-8) + double-buffered Ab (breaks write->read chain);
// FFN chunk order staggered by block parity + h1 dbuf (4 barriers not 8).
// LDS layout: ssfw [0,25600) ; Ab [25600,46080) (8 waves x 2 bufs x 16x40 shorts) ;
// bias [46080,47744) ; z3s [47744,56448) ; z2s [56448,73344).
// h1a [0,8704) h1b [8704,17408) overlay dead attn scratch in FFN phase.
__global__ __launch_bounds__(512, 4) void k_at(const short* __restrict__ qbf,
    const short* __restrict__ kbf, const short* __restrict__ vtb,
    const float* __restrict__ rel_bias, const short* __restrict__ tb,
    const float* __restrict__ bil_b, const float* __restrict__ xnhwc,
    const float* __restrict__ g2, const float* __restrict__ b2ln,
    const short* __restrict__ w1bf, const float* __restrict__ b1,
    const short* __restrict__ w2bf, const float* __restrict__ b2,
    float* __restrict__ out) {
  __shared__ __align__(16) char smem[73344];
  short* h1a = (short*)smem;
  short* h1b = (short*)(smem + 8704);
  short* z3s = (short*)(smem + 47744);
  float* z2s = (float*)(smem + 56448);
  int tid = threadIdx.x;
  int bid = blockIdx.x;
  int l = xcd_band(bid);
  int half = l & 1, ny = l >> 1;
  int n = ny >> 6, y = ny & 63;
  int w16 = tid >> 6, lane = tid & 63;
  int quad = lane >> 4, r16 = lane & 15;
  size_t rowbase = (size_t)ny * 8192;
  int wm = w16 & 1, wn = w16 >> 1;
  int stripL = wm * 16;
  const short* tn = tb + (size_t)n * 17408;
  float xres[2][4];
#pragma unroll
  for (int nt = 0; nt < 2; ++nt)
#pragma unroll
    for (int r = 0; r < 4; ++r)
      xres[nt][r] = xnhwc[rowbase + (half * 32 + stripL + quad * 4 + r) * 128 +
                          wn * 32 + nt * 16 + r16];
  short8 tf[2][4];
  // ---------- attention phase: wave = (h, local strip) ----------
  {
    int h = w16 >> 1, swl = w16 & 1;
    int sg = half * 2 + swl;                    // global strip idx [0,4)
    int strip = sg * 16;
    float* ssfw = (float*)(smem + w16 * 3200);
    short* Ab = (short*)(smem + 25600 + w16 * 2560);   // 2 bufs x [16][40] bf16
    float* biasw = (float*)(smem + 46080 + w16 * 208);
    // batch-preload Q + all 14 K fragments
    const short* qrow = qbf + (size_t)n * 524288 + (size_t)y * 8192 + h * 32;
    const short* kbp = kbf + (size_t)n * 524288 + h * 32;
    short8 qf = *(const short8*)&qrow[(strip + r16) * 128 + quad * 8];
    short8 kf[7][2];
#pragma unroll
    for (int r = 0; r < 7; ++r) {
      int yyc = min(max(y + r - 3, 0), 63);
#pragma unroll
      for (int t = 0; t < 2; ++t) {
        int gxc = min(max((sg + t) * 16 + r16 - 3, 0), 63);
        kf[r][t] = *(const short8*)&kbp[(size_t)(yyc * 64 + gxc) * 128 + quad * 8];
      }
    }
    // LDS inits overlap loads in flight: zero BOTH Ab buffers (cells never written stay 0)
    {
      unsigned* ad = (unsigned*)Ab;
      for (int i = lane; i < 640; i += 64) ad[i] = 0u;
    }
    if (lane < 49) biasw[lane] = rel_bias[h * 49 + lane];
    // QK MFMA burst
#pragma unroll
    for (int r = 0; r < 7; ++r) {
      bool yok = (unsigned)(y + r - 3) < 64u;
#pragma unroll
      for (int t = 0; t < 2; ++t) {
        int xxc = (sg + t) * 16 + r16;
        bool ok = yok && ((unsigned)(xxc - 3) < 64u);
        floatx4 c = MFMA16(qf, kf[r][t], ((floatx4){0.f, 0.f, 0.f, 0.f}));
#pragma unroll
        for (int rr = 0; rr < 4; ++rr) {
          int lrow = quad * 4 + rr;
          int dx = xxc - (strip + lrow);
          if ((unsigned)dx < 7u) {
            float val = ok ? c[rr] : 0.f;       // reference zero-pads K
            ssfw[lrow * 50 + r * 7 + dx] = val + biasw[r * 7 + dx];
          }
        }
      }
    }
    // softmax over P=49 (4 lanes per row), normalized back to ssfw
    {
      int lrow = lane >> 2, sub = lane & 3;
      int p0 = sub * 12;
      float sv[13];
      float mx = -1e30f;
#pragma unroll
      for (int pi = 0; pi < 13; ++pi) {
        sv[pi] = ssfw[lrow * 50 + p0 + pi];
        mx = fmaxf(mx, sv[pi]);
      }
      mx = fmaxf(mx, __shfl_xor(mx, 1));
      mx = fmaxf(mx, __shfl_xor(mx, 2));
      float sum = 0.f;
#pragma unroll
      for (int pi = 0; pi < 13; ++pi) {
        float e = __expf(sv[pi] - mx);
        if (pi == 12 && sub != 3) e = 0.f;
        sv[pi] = e; sum += e;
      }
      sum += __shfl_xor(sum, 1);
      sum += __shfl_xor(sum, 2);
      float inv = 1.f / sum;
#pragma unroll
      for (int pi = 0; pi < 13; ++pi)
        if (pi < 12 || sub == 3) ssfw[lrow * 50 + p0 + pi] = sv[pi] * inv;
    }
    // ---- PV: single K=32 chunk anchored at x0 = strip-8; Ab double-buffered ----
    // A[row][k] nonzero only for k = row + dx + 5 (dx in [0,7), x = strip+row+dx-3 valid);
    // V reads at zero-A columns may touch adjacent rows' data -> multiplied by 0.
    floatx4 oacc[2] = {(floatx4){0.f, 0.f, 0.f, 0.f}, (floatx4){0.f, 0.f, 0.f, 0.f}};
    int lrow = lane >> 2, sub = lane & 3;
    const short* vbp = vtb + (size_t)(n * 128 + h * 32) * 4096;
    int xa = strip + lrow + sub - 3;            // x for dx = sub
    int xb = xa + 4;                            // x for dx = sub+4
    bool wa = (unsigned)xa < 64u;
    bool wb = (sub < 3) && ((unsigned)xb < 64u);
    int ka = lrow * 40 + lrow + sub + 5;
    int kb = ka + 4;
    long vco = (long)(strip - 8 + quad * 8);
    // scatter r=0 into buffer 0
    if (wa) Ab[ka] = f2bf(ssfw[lrow * 50 + sub]);
    if (wb) Ab[kb] = f2bf(ssfw[lrow * 50 + sub + 4]);
    short8 vf[2][2];                            // [parity][nt]
    {
      int yyc0 = min(max(y - 3, 0), 63);
#pragma unroll
      for (int nt = 0; nt < 2; ++nt)
        vf[0][nt] = *(const short8*)(vbp + (long)(nt * 16 + r16) * 4096 + (long)(yyc0 * 64) + vco);
    }
#pragma unroll
    for (int r = 0; r < 7; ++r) {
      if (r < 6) {                              // prefetch V(r+1) + scatter P(r+1) into other buffer
        int yycn = min(max(y + r - 2, 0), 63);
#pragma unroll
        for (int nt = 0; nt < 2; ++nt)
          vf[(r + 1) & 1][nt] = *(const short8*)(vbp + (long)(nt * 16 + r16) * 4096 + (long)(yycn * 64) + vco);
        short* AbN = Ab + ((r + 1) & 1) * 640;
        if (wa) AbN[ka] = f2bf(ssfw[lrow * 50 + (r + 1) * 7 + sub]);
        if (wb) AbN[kb] = f2bf(ssfw[lrow * 50 + (r + 1) * 7 + sub + 4]);
      }
      if ((unsigned)(y + r - 3) < 64u) {        // reference zero-pads V (wave-uniform guard)
        short8 af = *(const short8*)&Ab[(r & 1) * 640 + r16 * 40 + quad * 8];
#pragma unroll
        for (int nt = 0; nt < 2; ++nt)
          oacc[nt] = MFMA16(af, vf[r & 1][nt], oacc[nt]);
      }
    }
    // prefetch bilinear t fragments: latency hides under z3s writes + barrier
#pragma unroll
    for (int nt = 0; nt < 2; ++nt)
#pragma unroll
      for (int kk = 0; kk < 4; ++kk)
        tf[nt][kk] = *(const short8*)&tn[(wn * 32 + nt * 16 + r16) * 136 + kk * 32 + quad * 8];
#pragma unroll
    for (int nt = 0; nt < 2; ++nt)
#pragma unroll
      for (int rr = 0; rr < 4; ++rr) {
        int pxl = swl * 16 + quad * 4 + rr;
        z3s[pxl * 136 + h * 32 + nt * 16 + r16] = f2bf(oacc[nt][rr]);
      }
  }
  __syncthreads();
  // ---------- bilinear (B frags already in tf) ----------
  {
    short8 a[4];
#pragma unroll
    for (int kk = 0; kk < 4; ++kk)
      a[kk] = *(const short8*)&z3s[(stripL + r16) * 136 + kk * 32 + quad * 8];
#pragma unroll
    for (int nt = 0; nt < 2; ++nt) {
      int o0 = wn * 32 + nt * 16;
      floatx4 acc = {0.f, 0.f, 0.f, 0.f};
#pragma unroll
      for (int kk = 0; kk < 4; ++kk)
        acc = MFMA16(a[kk], tf[nt][kk], acc);
      float bb = bil_b[o0 + r16];
#pragma unroll
      for (int r = 0; r < 4; ++r) {
        int pxl = stripL + quad * 4 + r;
        z2s[pxl * 132 + o0 + r16] = acc[r] + bb + xres[nt][r];
      }
    }
  }
  __syncthreads();
  // ---------- LN2 -> z3s bf16 (first FFN chunk's w1 prefetch issued first) ----------
  int ck0 = (bid & 1) * 2;                      // stagger start chunk by block parity
  short8 wA[2][4];
#pragma unroll
  for (int nt = 0; nt < 2; ++nt)
#pragma unroll
    for (int kk = 0; kk < 4; ++kk)
      wA[nt][kk] = *(const short8*)&w1bf[(ck0 * 128 + wn * 32 + nt * 16 + r16) * 136 + kk * 32 + quad * 8];
  {
    int px = tid >> 4, cl = tid & 15;
    float4 v0 = *(const float4*)&z2s[px * 132 + cl * 8];
    float4 v1 = *(const float4*)&z2s[px * 132 + cl * 8 + 4];
    float s = v0.x + v0.y + v0.z + v0.w + v1.x + v1.y + v1.z + v1.w;
    float sq = dot4(v0, v0) + dot4(v1, v1);
    s += __shfl_xor(s, 1);  sq += __shfl_xor(sq, 1);
    s += __shfl_xor(s, 2);  sq += __shfl_xor(sq, 2);
    s += __shfl_xor(s, 4);  sq += __shfl_xor(sq, 4);
    s += __shfl_xor(s, 8);  sq += __shfl_xor(sq, 8);
    float m = s * (1.f / 128.f);
    float var = sq * (1.f / 128.f) - m * m;
    float rr = rsqrtf(var + EPS);
    int c0 = cl * 8;
    short t8[8];
#pragma unroll
    for (int j = 0; j < 8; ++j) {
      float vv = (j < 4) ? (&v0.x)[j] : (&v1.x)[j - 4];
      t8[j] = f2bf((vv - m) * rr * g2[c0 + j] + b2ln[c0 + j]);
    }
    *(uint4*)&z3s[px * 136 + c0] = *(uint4*)t8;
  }
  __syncthreads();
  // ---------- FFN: 4 chunks (order staggered by parity), h1 dbuf -> 1 barrier/chunk ----------
  floatx4 zacc[2];
  zacc[0] = (floatx4){0.f, 0.f, 0.f, 0.f};
  zacc[1] = (floatx4){0.f, 0.f, 0.f, 0.f};
#pragma unroll
  for (int i = 0; i < 4; ++i) {
    int ck = (ck0 + i) & 3;
    int fc = ck * 128;
    short* h1w = (i & 1) ? h1b : h1a;
    short8 wB[2][4];
#pragma unroll
    for (int nt = 0; nt < 2; ++nt)
#pragma unroll
      for (int kk = 0; kk < 4; ++kk)
        wB[nt][kk] = *(const short8*)&w2bf[(ck * 128 + wn * 32 + nt * 16 + r16) * 136 + kk * 32 + quad * 8];
    float bb1v[2];
    bb1v[0] = b1[fc + wn * 32 + r16];
    bb1v[1] = b1[fc + wn * 32 + 16 + r16];
    short8 a3[4];
#pragma unroll
    for (int kk = 0; kk < 4; ++kk)
      a3[kk] = *(const short8*)&z3s[(stripL + r16) * 136 + kk * 32 + quad * 8];
    floatx4 hacc[2];
#pragma unroll
    for (int nt = 0; nt < 2; ++nt) {
      hacc[nt] = (floatx4){0.f, 0.f, 0.f, 0.f};
#pragma unroll
      for (int kk = 0; kk < 4; ++kk)
        hacc[nt] = MFMA16(a3[kk], wA[nt][kk], hacc[nt]);
    }
    if (i < 3) {                                // prefetch next chunk's w1 during gelu
      int ckn = (ck0 + i + 1) & 3;
#pragma unroll
      for (int nt = 0; nt < 2; ++nt)
#pragma unroll
        for (int kk = 0; kk < 4; ++kk)
          wA[nt][kk] = *(const short8*)&w1bf[(ckn * 128 + wn * 32 + nt * 16 + r16) * 136 + kk * 32 + quad * 8];
    }
#pragma unroll
    for (int nt = 0; nt < 2; ++nt) {
      int f0 = wn * 32 + nt * 16;
#pragma unroll
      for (int r = 0; r < 4; ++r) {
        float hv = hacc[nt][r] + bb1v[nt];
        float ge = 0.5f * hv * (1.f + erff(hv * 0.70710678118f));
        h1w[(stripL + quad * 4 + r) * 136 + f0 + r16] = f2bf(ge);
      }
    }
    __syncthreads();   // this chunk's h1 visible; other buffer free for next chunk
    short8 ah[4];
#pragma unroll
    for (int kk = 0; kk < 4; ++kk)
      ah[kk] = *(const short8*)&h1w[(stripL + r16) * 136 + kk * 32 + quad * 8];
#pragma unroll
    for (int nt = 0; nt < 2; ++nt)
#pragma unroll
      for (int kk = 0; kk < 4; ++kk)
        zacc[nt] = MFMA16(ah[kk], wB[nt][kk], zacc[nt]);
    // no trailing barrier: next chunk writes the other h1 buffer
  }
  // ---------- epilogue: direct float4 stores ----------
#pragma unroll
  for (int nt = 0; nt < 2; ++nt) {
    int o = wn * 32 + nt * 16 + r16;
    float bb = b2[o];
    float res[4];
#pragma unroll
    for (int r = 0; r < 4; ++r)
      res[r] = zacc[nt][r] + bb + z2s[(stripL + quad * 4 + r) * 132 + o];
    *(float4*)&out[(((size_t)(n * 128 + o)) * 64 + y) * 64 + half * 32 + stripL + quad * 4] =
        *(float4*)res;
  }
}

// ----------------------------------------------------------------
extern "C" void kernel_launch(void* const* d_in, const int* in_sizes, int n_in,
                              void* d_out, int out_size, void* d_ws, size_t ws_size,
                              hipStream_t stream) {
  const float* x        = (const float*)d_in[0];
  const float* qcoeff   = (const float*)d_in[1];
  const float* wq       = (const float*)d_in[2];
  const float* bq       = (const float*)d_in[3];
  const float* wk       = (const float*)d_in[4];
  const float* bk       = (const float*)d_in[5];
  const float* wv       = (const float*)d_in[6];
  const float* bv       = (const float*)d_in[7];
  const float* rel_bias = (const float*)d_in[8];
  const float* ln1_g    = (const float*)d_in[9];
  const float* ln1_b    = (const float*)d_in[10];
  const float* bil_w    = (const float*)d_in[11];
  const float* bil_b    = (const float*)d_in[12];
  const float* ln2_g    = (const float*)d_in[13];
  const float* ln2_b    = (const float*)d_in[14];
  const float* w1       = (const float*)d_in[15];
  const float* b1       = (const float*)d_in[16];
  const float* w2       = (const float*)d_in[17];
  const float* b2       = (const float*)d_in[18];
  float* out = (float*)d_out;

  float* ws = (float*)d_ws;
  float* x_nhwc = ws;                    // [N,H,W,E] fp32
  short* qbf = (short*)(ws + 2 * SZ);
  short* kbf = qbf + SZ;
  short* vtb = kbf + SZ;
  short* bf     = (short*)(ws + 4 * SZ);
  short* tb     = bf;                    // [4][128][136]
  short* w1bf   = bf + 4 * 17408;        // [512][136]
  short* w2bf   = w1bf + 512 * 136;      // [4][128][136]

  k_qkvln<<<512, 512, 0, stream>>>(x, ln1_g, ln1_b, wq, wk, wv, bq, bk, bv,
                                   w1, w2, bil_w, qcoeff,
                                   x_nhwc, qbf, kbf, vtb, w1bf, w2bf, tb);
  k_at<<<512, 512, 0, stream>>>(qbf, kbf, vtb, rel_bias, tb, bil_b, x_nhwc,
                                ln2_g, ln2_b, w1bf, b1, w2bf, b2, out);
}